// Round 1
// baseline (94.497 us; speedup 1.0000x reference)
//
#include <hip/hip_runtime.h>

#define NQ 4
#define DIM 16
#define NCOEF 136  // 16*17/2 folded symmetric entries

struct cplx { float r, i; };
__device__ inline cplx cmul(cplx a, cplx b) { return {a.r*b.r - a.i*b.i, a.r*b.i + a.i*b.r}; }
__device__ inline cplx cadd(cplx a, cplx b) { return {a.r + b.r, a.i + b.i}; }

// Build U (16x16 complex) for the shared circuit, then emit folded quadratic-form
// coefficients: coef[u*4 + w] for u-th (j<=k) pair, output w.
__global__ void setup_kernel(const float* __restrict__ wt, float* __restrict__ coef) {
    __shared__ float Ur[DIM][DIM];
    __shared__ float Ui[DIM][DIM];
    int col = threadIdx.x;
    if (col < DIM) {
        // Evolve basis column |col> through the shared circuit.
        float ar[DIM], ai[DIM];
#pragma unroll
        for (int i = 0; i < DIM; ++i) { ar[i] = 0.f; ai[i] = 0.f; }
        ar[col] = 1.f;
        for (int l = 0; l < 2; ++l) {
            for (int q = 0; q < NQ; ++q) {
                float tx = wt[(l * 4 + q) * 3 + 0];
                float ty = wt[(l * 4 + q) * 3 + 1];
                float tz = wt[(l * 4 + q) * 3 + 2];
                float cx = cosf(0.5f * tx), sx = sinf(0.5f * tx);
                float cy = cosf(0.5f * ty), sy = sinf(0.5f * ty);
                float cz = cosf(0.5f * tz), sz = sinf(0.5f * tz);
                // Rx = [[cx, -i sx], [-i sx, cx]]
                cplx Rx[2][2] = {{{cx, 0.f}, {0.f, -sx}}, {{0.f, -sx}, {cx, 0.f}}};
                // Ry = [[cy, -sy], [sy, cy]]
                cplx Ry[2][2] = {{{cy, 0.f}, {-sy, 0.f}}, {{sy, 0.f}, {cy, 0.f}}};
                // Rz = diag(cz - i sz, cz + i sz)
                cplx Rz[2][2] = {{{cz, -sz}, {0.f, 0.f}}, {{0.f, 0.f}, {cz, sz}}};
                cplx T[2][2], G[2][2];
                for (int r = 0; r < 2; ++r)
                    for (int c = 0; c < 2; ++c)
                        T[r][c] = cadd(cmul(Ry[r][0], Rx[0][c]), cmul(Ry[r][1], Rx[1][c]));
                for (int r = 0; r < 2; ++r)
                    for (int c = 0; c < 2; ++c)
                        G[r][c] = cadd(cmul(Rz[r][0], T[0][c]), cmul(Rz[r][1], T[1][c]));
                int pos = 3 - q, mask = 1 << pos;
                for (int idx = 0; idx < DIM; ++idx) {
                    if (idx & mask) continue;
                    int i1 = idx | mask;
                    cplx a0 = {ar[idx], ai[idx]}, a1 = {ar[i1], ai[i1]};
                    cplx n0 = cadd(cmul(G[0][0], a0), cmul(G[0][1], a1));
                    cplx n1 = cadd(cmul(G[1][0], a0), cmul(G[1][1], a1));
                    ar[idx] = n0.r; ai[idx] = n0.i;
                    ar[i1] = n1.r;  ai[i1] = n1.i;
                }
            }
            // CNOT ring: control q, target (q+1)%4 — amplitude swap where control set.
            for (int q = 0; q < NQ; ++q) {
                int cpos = 3 - q, tpos = 3 - ((q + 1) & 3);
                int tmask = 1 << tpos;
                for (int idx = 0; idx < DIM; ++idx) {
                    if (((idx >> cpos) & 1) && !((idx >> tpos) & 1)) {
                        int i1 = idx | tmask;
                        float tr = ar[idx]; ar[idx] = ar[i1]; ar[i1] = tr;
                        float ti = ai[idx]; ai[idx] = ai[i1]; ai[i1] = ti;
                    }
                }
            }
        }
        for (int i = 0; i < DIM; ++i) { Ur[i][col] = ar[i]; Ui[i][col] = ai[i]; }
    }
    __syncthreads();
    // A_w[j][k] = sum_idx sign_w(idx) * (Ur[idx][j]Ur[idx][k] + Ui[idx][j]Ui[idx][k])
    for (int id = threadIdx.x; id < 4 * NCOEF; id += blockDim.x) {
        int u = id >> 2, wo = id & 3;
        int j = 0, rem = u;
        while (rem >= DIM - j) { rem -= DIM - j; ++j; }
        int k = j + rem;
        float acc = 0.f;
        for (int idx = 0; idx < DIM; ++idx) {
            float sgn = ((idx >> (3 - wo)) & 1) ? -1.f : 1.f;
            acc += sgn * (Ur[idx][j] * Ur[idx][k] + Ui[idx][j] * Ui[idx][k]);
        }
        coef[id] = (j == k) ? acc : 2.f * acc;
    }
}

__device__ inline void build_state(float4 xv, float* s) {
    float c0, s0, c1, s1, c2, s2, c3, s3;
    __sincosf(0.5f * xv.x, &s0, &c0);
    __sincosf(0.5f * xv.y, &s1, &c1);
    __sincosf(0.5f * xv.z, &s2, &c2);
    __sincosf(0.5f * xv.w, &s3, &c3);
    float p01[4] = {c0 * c1, c0 * s1, s0 * c1, s0 * s1};
    float p23[4] = {c2 * c3, c2 * s3, s2 * c3, s2 * s3};
#pragma unroll
    for (int a = 0; a < 4; ++a)
#pragma unroll
        for (int b = 0; b < 4; ++b)
            s[a * 4 + b] = p01[a] * p23[b];
}

__global__ __launch_bounds__(256) void qsim_kernel(const float4* __restrict__ x,
                                                   const float4* __restrict__ coef,
                                                   float4* __restrict__ out, int nthreads) {
    int tid = blockIdx.x * blockDim.x + threadIdx.x;
    if (tid >= nthreads) return;
    float4 xa = x[2 * tid + 0];
    float4 xb = x[2 * tid + 1];
    float sA[DIM], sB[DIM];
    build_state(xa, sA);
    build_state(xb, sB);
    float a0 = 0.f, a1 = 0.f, a2 = 0.f, a3 = 0.f;
    float b0 = 0.f, b1 = 0.f, b2 = 0.f, b3 = 0.f;
    int t = 0;
#pragma unroll
    for (int j = 0; j < DIM; ++j) {
#pragma unroll
        for (int k = j; k < DIM; ++k, ++t) {
            float4 c = coef[t];  // wave-uniform address -> expect s_load_dwordx4
            float pa = sA[j] * sA[k];
            float pb = sB[j] * sB[k];
            a0 = fmaf(c.x, pa, a0);
            a1 = fmaf(c.y, pa, a1);
            a2 = fmaf(c.z, pa, a2);
            a3 = fmaf(c.w, pa, a3);
            b0 = fmaf(c.x, pb, b0);
            b1 = fmaf(c.y, pb, b1);
            b2 = fmaf(c.z, pb, b2);
            b3 = fmaf(c.w, pb, b3);
        }
    }
    out[2 * tid + 0] = make_float4(a0, a1, a2, a3);
    out[2 * tid + 1] = make_float4(b0, b1, b2, b3);
}

extern "C" void kernel_launch(void* const* d_in, const int* in_sizes, int n_in,
                              void* d_out, int out_size, void* d_ws, size_t ws_size,
                              hipStream_t stream) {
    const float* x = (const float*)d_in[0];
    const float* wt = (const float*)d_in[1];
    float* out = (float*)d_out;
    float* coef = (float*)d_ws;  // 544 floats = 2176 B

    setup_kernel<<<1, 256, 0, stream>>>(wt, coef);

    int B = in_sizes[0] / NQ;      // 2^20 samples
    int nthreads = B / 2;          // 2 samples per thread
    int blocks = (nthreads + 255) / 256;
    qsim_kernel<<<blocks, 256, 0, stream>>>((const float4*)x, (const float4*)coef,
                                            (float4*)out, nthreads);
}